// Round 2
// baseline (368.815 us; speedup 1.0000x reference)
//
#include <hip/hip_runtime.h>
#include <math.h>

#define CC 64
#define HH 256
#define WW 256
#define HWX (HH * WW)      // 65536
#define BB 16
#define TH 16              // output rows per block
#define TROWS (TH + 2)     // 18 rows incl. 1-row halo each side

// One fused kernel: 1x1 conv (64->2) + exp + 3x3 edge-clamped box-sum + divide.
// Block = 1 image x 16-row tile. 576 threads = 9 waves: thread (wg, g) owns
// w-range [4*wg, 4*wg+4) and tile rows {g, g+9} (18 rows / 9 groups).
// Halo rows are recomputed (12.5% extra x reads) instead of spilling e/s to
// global — avoids d_ws entirely and the second launch.
__global__ __launch_bounds__(576) void fused_sdm_kernel(
    const float* __restrict__ x,
    const float* __restrict__ Wt,     // [2,64]
    const float* __restrict__ bias,   // [2]
    float* __restrict__ out)
{
    __shared__ float w0[CC];
    __shared__ float w1[CC];
    __shared__ float sS[TROWS][WW];   // e0+e1 (denominator field)
    __shared__ float sE[TROWS][WW];   // e0   (numerator)

    const int tid = threadIdx.x;
    if (tid < CC)           w0[tid]      = Wt[tid];
    else if (tid < 2 * CC)  w1[tid - CC] = Wt[tid];
    __syncthreads();

    const float b0 = bias[0];
    const float b1 = bias[1];

    const int bimg = blockIdx.x >> 4;     // 16 tiles per image
    const int tile = blockIdx.x & 15;
    const int h0   = tile * TH;           // first output row of this tile

    const int wg = tid & 63;              // 0..63 (wave-lane == w-group)
    const int g  = tid >> 6;              // 0..8  (wave index == row-group)
    const int w4 = wg << 2;

    const int r0 = g;                     // tile rows owned by this thread
    const int r1 = g + 9;

    int h_a = h0 + r0 - 1; h_a = h_a < 0 ? 0 : (h_a > HH - 1 ? HH - 1 : h_a);
    int h_b = h0 + r1 - 1; h_b = h_b < 0 ? 0 : (h_b > HH - 1 ? HH - 1 : h_b);

    const float* xb = x + (size_t)bimg * CC * HWX;
    const int offA = h_a * WW + w4;
    const int offB = h_b * WW + w4;

    float4 A0 = make_float4(b0, b0, b0, b0);
    float4 B0 = A0;
    float4 A1 = make_float4(b1, b1, b1, b1);
    float4 B1 = A1;

    #pragma unroll 4
    for (int c = 0; c < CC; ++c) {
        const float4 va = *(const float4*)(xb + (size_t)c * HWX + offA);
        const float4 vb = *(const float4*)(xb + (size_t)c * HWX + offB);
        const float wc0 = w0[c];
        const float wc1 = w1[c];
        A0.x = fmaf(va.x, wc0, A0.x);
        A0.y = fmaf(va.y, wc0, A0.y);
        A0.z = fmaf(va.z, wc0, A0.z);
        A0.w = fmaf(va.w, wc0, A0.w);
        A1.x = fmaf(va.x, wc1, A1.x);
        A1.y = fmaf(va.y, wc1, A1.y);
        A1.z = fmaf(va.z, wc1, A1.z);
        A1.w = fmaf(va.w, wc1, A1.w);
        B0.x = fmaf(vb.x, wc0, B0.x);
        B0.y = fmaf(vb.y, wc0, B0.y);
        B0.z = fmaf(vb.z, wc0, B0.z);
        B0.w = fmaf(vb.w, wc0, B0.w);
        B1.x = fmaf(vb.x, wc1, B1.x);
        B1.y = fmaf(vb.y, wc1, B1.y);
        B1.z = fmaf(vb.z, wc1, B1.z);
        B1.w = fmaf(vb.w, wc1, B1.w);
    }

    // exp + write the two LDS fields for both owned rows
    float4 EA, EB, SA, SB;
    EA.x = __expf(A0.x); EA.y = __expf(A0.y); EA.z = __expf(A0.z); EA.w = __expf(A0.w);
    EB.x = __expf(B0.x); EB.y = __expf(B0.y); EB.z = __expf(B0.z); EB.w = __expf(B0.w);
    SA.x = EA.x + __expf(A1.x); SA.y = EA.y + __expf(A1.y);
    SA.z = EA.z + __expf(A1.z); SA.w = EA.w + __expf(A1.w);
    SB.x = EB.x + __expf(B1.x); SB.y = EB.y + __expf(B1.y);
    SB.z = EB.z + __expf(B1.z); SB.w = EB.w + __expf(B1.w);

    *(float4*)&sE[r0][w4] = EA;
    *(float4*)&sS[r0][w4] = SA;
    *(float4*)&sE[r1][w4] = EB;
    *(float4*)&sS[r1][w4] = SB;
    __syncthreads();

    // 3x3 box sum + divide for owned OUTPUT rows (tile rows 1..16)
    const int wl = (wg == 0)  ? 0      : w4 - 1;   // clamped left col
    const int wr = (wg == 63) ? WW - 1 : w4 + 4;   // clamped right col
    float* outb = out + (size_t)bimg * HWX;

    #pragma unroll
    for (int k = 0; k < 2; ++k) {
        const int r = k ? r1 : r0;
        if (r < 1 || r > TH) continue;   // wave-uniform (g-dependent only)

        float cs0 = 0.f, cs1 = 0.f, cs2 = 0.f, cs3 = 0.f, cs4 = 0.f, cs5 = 0.f;
        #pragma unroll
        for (int dr = -1; dr <= 1; ++dr) {
            const float4 m = *(const float4*)&sS[r + dr][w4];  // b128, conflict-free
            cs0 += sS[r + dr][wl];
            cs1 += m.x; cs2 += m.y; cs3 += m.z; cs4 += m.w;
            cs5 += sS[r + dr][wr];
        }
        const float4 e = *(const float4*)&sE[r][w4];
        float4 o;
        o.x = e.x / (cs0 + cs1 + cs2);
        o.y = e.y / (cs1 + cs2 + cs3);
        o.z = e.z / (cs2 + cs3 + cs4);
        o.w = e.w / (cs3 + cs4 + cs5);
        *(float4*)(outb + (size_t)(h0 + r - 1) * WW + w4) = o;
    }
}

extern "C" void kernel_launch(void* const* d_in, const int* in_sizes, int n_in,
                              void* d_out, int out_size, void* d_ws, size_t ws_size,
                              hipStream_t stream) {
    const float* x    = (const float*)d_in[0];
    const float* Wt   = (const float*)d_in[1];
    const float* bias = (const float*)d_in[2];
    float* out = (float*)d_out;

    const int blocks = BB * (HH / TH);   // 16 images x 16 tiles = 256
    fused_sdm_kernel<<<blocks, 576, 0, stream>>>(x, Wt, bias, out);
}